// Round 9
// baseline (580.919 us; speedup 1.0000x reference)
//
#include <hip/hip_runtime.h>
#include <hip/hip_cooperative_groups.h>

namespace cg = cooperative_groups;

#define N_NODES 50000
#define IN_CH 128
#define HID 128
#define OUT_CH 40
#define N_LAYERS 3
#define N_EDGES 600000
#define DSTRIDE 64    // fixed col slots/node; P(Poisson(12) > 64) ~ 1e-30
#define DEGSTRIDE 16  // 64B per counter
#define CHUNK 6250    // nodes per XCD class (N/8)
#define W_ITEMS (6 * 16384 + 48 * 128)

typedef __attribute__((ext_vector_type(8))) short short8;
typedef __attribute__((ext_vector_type(4))) float floatx4;

static __device__ __forceinline__ unsigned short f32_to_bf16(float f) {
  unsigned u = __float_as_uint(f);
  unsigned r = 0x7FFFu + ((u >> 16) & 1u);  // RNE
  return (unsigned short)((u + r) >> 16);
}
static __device__ __forceinline__ float bf16_to_f32(unsigned short h) {
  return __uint_as_float(((unsigned)h) << 16);
}

// ===== shared device helpers (identical code for coop + fallback paths) ====

// W transpose item o: WT bf16 [n][k] from W1/W2 f32 [k][n]; then WcT padded.
static __device__ __forceinline__ void w_transpose_item(
    int o, const float* __restrict__ W1, const float* __restrict__ W2,
    const float* __restrict__ Wc, unsigned short* __restrict__ WT,
    unsigned short* __restrict__ WcT) {
  if (o < 6 * 16384) {
    int mat = o >> 14;
    int r = o & 16383;
    int n = r >> 7;
    int k = r & 127;
    const float* W = (mat < 3) ? (W1 + (size_t)mat * 16384)
                               : (W2 + (size_t)(mat - 3) * 16384);
    WT[(size_t)mat * 16384 + (size_t)n * 128 + k] =
        f32_to_bf16(W[(size_t)k * 128 + n]);
  } else if (o < W_ITEMS) {
    int r = o - 6 * 16384;
    int n = r >> 7;
    int k = r & 127;
    float v = (n < OUT_CH) ? Wc[(size_t)k * OUT_CH + n] : 0.0f;
    WcT[(size_t)n * 128 + k] = f32_to_bf16(v);
  }
}

// CSR edge quad (base..base+3), filtered to dst in [lo,hi).
static __device__ __forceinline__ void csr_quad(
    int base, int lo, int hi, const int* __restrict__ ei,
    int* __restrict__ deg, int* __restrict__ col) {
  int4 s4 = *(const int4*)(ei + base);
  int4 d4 = *(const int4*)(ei + N_EDGES + base);
  if (d4.x >= lo && d4.x < hi) {
    int p = atomicAdd(&deg[(size_t)d4.x * DEGSTRIDE], 1);
    col[(size_t)d4.x * DSTRIDE + p] = s4.x;
  }
  if (d4.y >= lo && d4.y < hi) {
    int p = atomicAdd(&deg[(size_t)d4.y * DEGSTRIDE], 1);
    col[(size_t)d4.y * DSTRIDE + p] = s4.y;
  }
  if (d4.z >= lo && d4.z < hi) {
    int p = atomicAdd(&deg[(size_t)d4.z * DEGSTRIDE], 1);
    col[(size_t)d4.z * DSTRIDE + p] = s4.z;
  }
  if (d4.w >= lo && d4.w < hi) {
    int p = atomicAdd(&deg[(size_t)d4.w * DEGSTRIDE], 1);
    col[(size_t)d4.w * DSTRIDE + p] = s4.w;
  }
}

// R8-proven 2-node aggregate: lane owns 2 channels of nodes n0,n0+1; one
// 256B row per gather, 32 independent gathers in flight; deg/col wave-
// uniform via readfirstlane; tail clamps to phantom zero row N_NODES.
static __device__ __forceinline__ void aggr2(
    const unsigned short* __restrict__ h, const int* __restrict__ deg,
    const int* __restrict__ col, unsigned short* __restrict__ z,
    int n0raw, int q) {
  int n0 = __builtin_amdgcn_readfirstlane(n0raw);
  int n1 = n0 + 1;
  const size_t co = (size_t)q * 2;
  ushort2 sv0 = *(const ushort2*)(h + (size_t)n0 * 128 + co);
  ushort2 sv1 = *(const ushort2*)(h + (size_t)n1 * 128 + co);
  float ax0[4], ay0[4], ax1[4], ay1[4];
#pragma unroll
  for (int k = 0; k < 4; ++k) { ax0[k] = 0.f; ay0[k] = 0.f; ax1[k] = 0.f; ay1[k] = 0.f; }
  ax0[0] = bf16_to_f32(sv0.x);
  ay0[0] = bf16_to_f32(sv0.y);
  ax1[0] = bf16_to_f32(sv1.x);
  ay1[0] = bf16_to_f32(sv1.y);
  int dg0 = __builtin_amdgcn_readfirstlane(deg[(size_t)n0 * DEGSTRIDE]);
  int dg1 = __builtin_amdgcn_readfirstlane(deg[(size_t)n1 * DEGSTRIDE]);
  int cnt = ((dg0 > dg1 ? dg0 : dg1) + 15) & ~15;
  const int* cp0 = col + (size_t)n0 * DSTRIDE;
  const int* cp1 = col + (size_t)n1 * DSTRIDE;
  for (int i = 0; i < cnt; i += 16) {
    int ss0[16], ss1[16];
#pragma unroll
    for (int k = 0; k < 16; ++k) {
      int sl0 = cp0[i + k];  // in-bounds; garbage beyond dg clamped below
      int sl1 = cp1[i + k];
      ss0[k] = __builtin_amdgcn_readfirstlane((i + k < dg0) ? sl0 : N_NODES);
      ss1[k] = __builtin_amdgcn_readfirstlane((i + k < dg1) ? sl1 : N_NODES);
    }
    ushort2 v0[16], v1[16];
#pragma unroll
    for (int k = 0; k < 16; ++k) {
      v0[k] = *(const ushort2*)(h + (size_t)ss0[k] * 128 + co);
      v1[k] = *(const ushort2*)(h + (size_t)ss1[k] * 128 + co);
    }
#pragma unroll
    for (int k = 0; k < 16; ++k) {
      ax0[k & 3] += bf16_to_f32(v0[k].x);
      ay0[k & 3] += bf16_to_f32(v0[k].y);
      ax1[k & 3] += bf16_to_f32(v1[k].x);
      ay1[k & 3] += bf16_to_f32(v1[k].y);
    }
  }
  ushort2 o0, o1;
  o0.x = f32_to_bf16((ax0[0] + ax0[1]) + (ax0[2] + ax0[3]));
  o0.y = f32_to_bf16((ay0[0] + ay0[1]) + (ay0[2] + ay0[3]));
  o1.x = f32_to_bf16((ax1[0] + ax1[1]) + (ax1[2] + ax1[3]));
  o1.y = f32_to_bf16((ay1[0] + ay1[1]) + (ay1[2] + ay1[3]));
  *(ushort2*)(z + (size_t)n0 * 128 + co) = o0;
  *(ushort2*)(z + (size_t)n1 * 128 + co) = o1;
}

// MLP 64-row tile: T-rows wave-private; Wl staged per GEMM from L2-hot WT.
// Frag layouts (measured m89/m91): A/B [idx=lane&15][k=(lane>>4)*8+j];
// C/D row=(lane>>4)*4+reg, col=lane&15.
template <bool LAST>
static __device__ __forceinline__ void mlp_tile(
    unsigned short (&Wl)[128][136], unsigned short (&T)[64][136],
    const unsigned short* __restrict__ A, const unsigned short* __restrict__ WT1,
    const float* __restrict__ b1, const unsigned short* __restrict__ WT2,
    const float* __restrict__ b2, unsigned short* __restrict__ Z,
    const unsigned short* __restrict__ WcT, const float* __restrict__ bc,
    float* __restrict__ out, int row0, int tid) {
  const int w = tid >> 6;
  const int lane = tid & 63;
  const int qg = lane >> 4;
  const int ln = lane & 15;
  const int rbase = w * 16;
  const int r0 = row0 + rbase + ln;
  const short8 zero8 = {0, 0, 0, 0, 0, 0, 0, 0};

  // ---- stage WT1 -> Wl ----
#pragma unroll
  for (int j = 0; j < 8; ++j) {
    int slot = tid + j * 256;
    int row = slot >> 4;
    int kb = slot & 15;
    *(short8*)&Wl[row][kb * 8] = *(const short8*)(WT1 + (size_t)row * 128 + kb * 8);
  }
  __syncthreads();

  // ---- GEMM1: A direct-global, B from LDS ----
  floatx4 acc[8];
#pragma unroll
  for (int ct = 0; ct < 8; ++ct) acc[ct] = (floatx4){0.f, 0.f, 0.f, 0.f};
#pragma unroll
  for (int ks = 0; ks < 4; ++ks) {
    const int koff = ks * 32 + qg * 8;
    short8 a = (r0 < N_NODES) ? *(const short8*)(A + (size_t)r0 * 128 + koff) : zero8;
#pragma unroll
    for (int ct = 0; ct < 8; ++ct) {
      short8 b = *(const short8*)&Wl[ct * 16 + ln][koff];
      acc[ct] = __builtin_amdgcn_mfma_f32_16x16x32_bf16(a, b, acc[ct], 0, 0, 0);
    }
  }
#pragma unroll
  for (int ct = 0; ct < 8; ++ct) {
    float bv = b1[ct * 16 + ln];
#pragma unroll
    for (int r = 0; r < 4; ++r) {
      float v = fmaxf(acc[ct][r] + bv, 0.0f);
      T[rbase + qg * 4 + r][ct * 16 + ln] = f32_to_bf16(v);
    }
  }

  // ---- restage Wl with WT2 ----
  __syncthreads();
#pragma unroll
  for (int j = 0; j < 8; ++j) {
    int slot = tid + j * 256;
    int row = slot >> 4;
    int kb = slot & 15;
    *(short8*)&Wl[row][kb * 8] = *(const short8*)(WT2 + (size_t)row * 128 + kb * 8);
  }
  __syncthreads();

  // ---- GEMM2: A from own T rows, B from LDS ----
  floatx4 acc2[8];
#pragma unroll
  for (int ct = 0; ct < 8; ++ct) acc2[ct] = (floatx4){0.f, 0.f, 0.f, 0.f};
#pragma unroll
  for (int ks = 0; ks < 4; ++ks) {
    const int koff = ks * 32 + qg * 8;
    short8 a = *(const short8*)&T[rbase + ln][koff];
#pragma unroll
    for (int ct = 0; ct < 8; ++ct) {
      short8 b = *(const short8*)&Wl[ct * 16 + ln][koff];
      acc2[ct] = __builtin_amdgcn_mfma_f32_16x16x32_bf16(a, b, acc2[ct], 0, 0, 0);
    }
  }
#pragma unroll
  for (int ct = 0; ct < 8; ++ct) {
    float bv = b2[ct * 16 + ln];
#pragma unroll
    for (int r = 0; r < 4; ++r) {
      float v = fmaxf(acc2[ct][r] + bv, 0.0f);
      T[rbase + qg * 4 + r][ct * 16 + ln] = f32_to_bf16(v);
    }
  }

  if (LAST) {
    // ---- GEMM3 (classifier): A from own T rows, B = WcT direct-global ----
    floatx4 acc3[3];
#pragma unroll
    for (int ct = 0; ct < 3; ++ct) acc3[ct] = (floatx4){0.f, 0.f, 0.f, 0.f};
#pragma unroll
    for (int ks = 0; ks < 4; ++ks) {
      const int koff = ks * 32 + qg * 8;
      short8 a = *(const short8*)&T[rbase + ln][koff];
#pragma unroll
      for (int ct = 0; ct < 3; ++ct) {
        short8 b = *(const short8*)(WcT + (size_t)(ct * 16 + ln) * 128 + koff);
        acc3[ct] = __builtin_amdgcn_mfma_f32_16x16x32_bf16(a, b, acc3[ct], 0, 0, 0);
      }
    }
#pragma unroll
    for (int ct = 0; ct < 3; ++ct) {
      int colg = ct * 16 + ln;
      if (colg < OUT_CH) {
        float bv = bc[colg];
#pragma unroll
        for (int r = 0; r < 4; ++r) {
          int row = row0 + rbase + qg * 4 + r;
          if (row < N_NODES) out[(size_t)row * OUT_CH + colg] = acc3[ct][r] + bv;
        }
      }
    }
  } else {
    __syncthreads();
#pragma unroll
    for (int j = 0; j < 4; ++j) {
      int slot = tid + j * 256;
      int row = slot >> 4;
      int kb = slot & 15;
      if (row0 + row < N_NODES) {
        short8 v = *(const short8*)&T[row][kb * 8];
        *(short8*)(Z + (size_t)(row0 + row) * 128 + kb * 8) = v;
      }
    }
  }
}

// ===================== persistent cooperative kernel =======================
// One dispatch replaces 8: phases separated by grid.sync() (device-scope
// rel-acq fence). XCD dst-chunk partition is exact here: the SAME physical
// block (same XCD L2) that builds a node's deg/col in phase 1 aggregates it
// in phase 2. Grid is runtime-sized to guaranteed co-residency.
__global__ __launch_bounds__(256) void gin_coop_kernel(
    const float* __restrict__ x, const float* __restrict__ W1,
    const float* __restrict__ W2, const float* __restrict__ Wc,
    const int* __restrict__ ei, const float* __restrict__ b1f,
    const float* __restrict__ b2f, const float* __restrict__ bcf,
    unsigned short* __restrict__ xbf, unsigned short* __restrict__ WT,
    unsigned short* __restrict__ WcT, unsigned short* __restrict__ hb0,
    unsigned short* __restrict__ hb1, int* __restrict__ deg,
    int* __restrict__ col, float* __restrict__ out) {
  cg::grid_group grid = cg::this_grid();
  __shared__ __align__(16) unsigned short Wl[128][136];
  __shared__ __align__(16) unsigned short T[64][136];
  const int nb = (int)gridDim.x;  // multiple of 32
  const int bid = (int)blockIdx.x;
  const int tid = (int)threadIdx.x;
  const int nthreads = nb * 256;

  // ===== phase 0: deg = 0, phantom rows =====
  for (int i = (bid * 256 + tid) * 4; i < N_NODES * DEGSTRIDE; i += nthreads * 4)
    *(int4*)(deg + i) = make_int4(0, 0, 0, 0);
  if (bid == 0) {
    if (tid < 128) xbf[(size_t)N_NODES * 128 + tid] = 0;
    else hb1[(size_t)N_NODES * 128 + (tid - 128)] = 0;
  }
  grid.sync();

  // ===== phase 1: csr (first nb/2 blocks, XCD-classed) + conv + W =====
  const int csrb = nb >> 1;  // multiple of 16 -> multiple of 8
  if (bid < csrb) {
    const int cls = bid & 7;
    const int lo = cls * CHUNK, hi = lo + CHUNK;
    const int stride = (csrb >> 3) * 256 * 4;
    for (int base = (((bid >> 3) * 256) + tid) * 4; base < N_EDGES; base += stride)
      csr_quad(base, lo, hi, ei, deg, col);
  } else {
    const int sb = bid - csrb;
    const int sthreads = (nb - csrb) * 256;
    for (int i = (sb * 256 + tid) * 4; i < N_NODES * 128; i += sthreads * 4) {
      float4 v = *(const float4*)(x + i);
      ushort4 o;
      o.x = f32_to_bf16(v.x); o.y = f32_to_bf16(v.y);
      o.z = f32_to_bf16(v.z); o.w = f32_to_bf16(v.w);
      *(ushort4*)(xbf + i) = o;
    }
    for (int o = sb * 256 + tid; o < W_ITEMS; o += sthreads)
      w_transpose_item(o, W1, W2, Wc, WT, WcT);
  }
  grid.sync();

  // ===== phase 2: 3 GIN layers =====
  const unsigned short* h = xbf;
  for (int l = 0; l < N_LAYERS; ++l) {
    // ---- aggregate h -> hb0 (same-XCD deg/col as phase 1) ----
    {
      const int xcd = bid & 7;
      const int wpx = (nb >> 3) * 4;               // waves per class
      const int wv = (bid >> 3) * 4 + (tid >> 6);  // wave idx in class
      const int q = tid & 63;
      for (int local = wv * 2; local < CHUNK; local += wpx * 2)
        aggr2(h, deg, col, hb0, xcd * CHUNK + local, q);
    }
    grid.sync();
    // ---- MLP tiles (64 rows each, grid-stride) ----
    const unsigned short* WT1 = WT + (size_t)l * 16384;
    const unsigned short* WT2 = WT + (size_t)(3 + l) * 16384;
    const float* b1 = b1f + (size_t)l * 128;
    const float* b2 = b2f + (size_t)l * 128;
    const int ntiles = (N_NODES + 63) / 64;  // 782
    if (l < N_LAYERS - 1) {
      for (int tile = bid; tile < ntiles; tile += nb) {
        __syncthreads();  // guard Wl/T vs previous tile iteration
        mlp_tile<false>(Wl, T, hb0, WT1, b1, WT2, b2, hb1, nullptr, nullptr,
                        nullptr, tile * 64, tid);
      }
      grid.sync();
      h = hb1;
    } else {
      for (int tile = bid; tile < ntiles; tile += nb) {
        __syncthreads();  // guard Wl/T vs previous tile iteration
        mlp_tile<true>(Wl, T, hb0, WT1, b1, WT2, b2, nullptr, WcT, bcf, out,
                       tile * 64, tid);
      }
    }
  }
}

// ===================== fallback (non-cooperative) path =====================
#define ZERO_BLOCKS 782
__global__ __launch_bounds__(256) void zero_deg_kernel(int* __restrict__ deg) {
  int i = (blockIdx.x * 256 + threadIdx.x) * 4;
  if (i < N_NODES * DEGSTRIDE) *(int4*)(deg + i) = make_int4(0, 0, 0, 0);
}

#define CSRB 1024
#define ECHUNKS 586
#define CONV_BLOCKS 6250
#define W_BLOCKS 408
__global__ __launch_bounds__(256) void prep_csr_kernel(
    const float* __restrict__ x, const float* __restrict__ W1,
    const float* __restrict__ W2, const float* __restrict__ Wc,
    const int* __restrict__ ei, unsigned short* __restrict__ xb,
    unsigned short* __restrict__ WT, unsigned short* __restrict__ WcT,
    unsigned short* __restrict__ hb1, int* __restrict__ deg,
    int* __restrict__ col) {
  const int b = blockIdx.x;
  const int t = threadIdx.x;
  if (b < CSRB) {
    const int lo = (b & 7) * CHUNK;
    const int hi = lo + CHUNK;
    for (int c = (b >> 3); c < ECHUNKS; c += (CSRB >> 3)) {
      int base = (c * 256 + t) * 4;
      if (base >= N_EDGES) continue;
      csr_quad(base, lo, hi, ei, deg, col);
    }
  } else if (b < CSRB + CONV_BLOCKS) {
    int i = ((b - CSRB) * 256 + t) * 4;
    if (i < N_NODES * 128) {
      float4 v = *(const float4*)(x + i);
      ushort4 o;
      o.x = f32_to_bf16(v.x); o.y = f32_to_bf16(v.y);
      o.z = f32_to_bf16(v.z); o.w = f32_to_bf16(v.w);
      *(ushort4*)(xb + i) = o;
    }
  } else if (b < CSRB + CONV_BLOCKS + W_BLOCKS) {
    w_transpose_item((b - CSRB - CONV_BLOCKS) * 256 + t, W1, W2, Wc, WT, WcT);
  } else {
    if (t < 128) xb[(size_t)N_NODES * 128 + t] = 0;
    else hb1[(size_t)N_NODES * 128 + (t - 128)] = 0;
  }
}

#define AGGR_GRID 6256
__global__ __launch_bounds__(256) void aggregate_kernel(
    const unsigned short* __restrict__ h, const int* __restrict__ deg,
    const int* __restrict__ col, unsigned short* __restrict__ z) {
  const int xcd = blockIdx.x & 7;
  const int idx = blockIdx.x >> 3;
  int local = idx * 8 + (threadIdx.x >> 6) * 2;
  if (local >= CHUNK) return;
  aggr2(h, deg, col, z, xcd * CHUNK + local, threadIdx.x & 63);
}

template <bool LAST>
__global__ __launch_bounds__(256) void layer_pair_kernel(
    const unsigned short* __restrict__ A, const unsigned short* __restrict__ WT1,
    const float* __restrict__ b1, const unsigned short* __restrict__ WT2,
    const float* __restrict__ b2, unsigned short* __restrict__ Z,
    const unsigned short* __restrict__ WcT, const float* __restrict__ bc,
    float* __restrict__ out) {
  __shared__ __align__(16) unsigned short Wl[128][136];
  __shared__ __align__(16) unsigned short T[64][136];
  mlp_tile<LAST>(Wl, T, A, WT1, b1, WT2, b2, Z, WcT, bc, out,
                 blockIdx.x * 64, threadIdx.x);
}

// ---------------------------------------------------------------------------
extern "C" void kernel_launch(void* const* d_in, const int* in_sizes, int n_in,
                              void* d_out, int out_size, void* d_ws,
                              size_t ws_size, hipStream_t stream) {
  const float* x = (const float*)d_in[0];
  const int* ei = (const int*)d_in[2];  // int32 [2, E]
  const float* W1 = (const float*)d_in[3];
  const float* b1 = (const float*)d_in[4];
  const float* W2 = (const float*)d_in[5];
  const float* b2 = (const float*)d_in[6];
  const float* Wc = (const float*)d_in[7];
  const float* bc = (const float*)d_in[8];
  float* out = (float*)d_out;

  // Node buffers have N+1 rows: row N_NODES is the phantom zero row.
  const size_t NF = (size_t)(N_NODES + 1) * 128;
  unsigned short* hb0 = (unsigned short*)d_ws;
  unsigned short* hb1 = hb0 + NF;
  unsigned short* xbf = hb1 + NF;
  unsigned short* WT = xbf + NF;         // 6*16384 bf16
  unsigned short* WcT = WT + 6 * 16384;  // 48*128 bf16
  int* deg = (int*)(WcT + 48 * 128);     // [N * DEGSTRIDE] (64B-padded ctrs)
  int* col = deg + (size_t)N_NODES * DEGSTRIDE;  // [N * DSTRIDE]

  // ---- runtime-sized cooperative launch (cached queries; host-side only) --
  static int coop_grid = -1;  // -1 unknown, 0 unsupported, >0 grid size
  if (coop_grid == -1) {
    int dev = 0;
    hipGetDevice(&dev);
    int coop = 0;
    hipDeviceGetAttribute(&coop, hipDeviceAttributeCooperativeLaunch, dev);
    int ncu = 0;
    hipDeviceGetAttribute(&ncu, hipDeviceAttributeMultiprocessorCount, dev);
    int maxb = 0;
    hipError_t e = hipOccupancyMaxActiveBlocksPerMultiprocessor(
        &maxb, (const void*)gin_coop_kernel, 256, 0);
    if (coop && e == hipSuccess && maxb > 0 && ncu > 0) {
      if (maxb > 3) maxb = 3;  // LDS math says 3; don't oversubscribe
      coop_grid = ncu * maxb;
      coop_grid -= coop_grid % 32;  // csr/class math needs multiple of 32
      if (coop_grid < 32) coop_grid = 0;
    } else {
      coop_grid = 0;
    }
  }

  if (coop_grid > 0) {
    void* args[] = {(void*)&x,   (void*)&W1,  (void*)&W2,  (void*)&Wc,
                    (void*)&ei,  (void*)&b1,  (void*)&b2,  (void*)&bc,
                    (void*)&xbf, (void*)&WT,  (void*)&WcT, (void*)&hb0,
                    (void*)&hb1, (void*)&deg, (void*)&col, (void*)&out};
    hipLaunchCooperativeKernel((const void*)gin_coop_kernel, dim3(coop_grid),
                               dim3(256), args, 0, stream);
    return;
  }

  // ---- fallback: proven R8 multi-kernel sequence ----
  const dim3 blk(256);
  const int pair_grid = (N_NODES + 63) / 64;  // 782
  zero_deg_kernel<<<ZERO_BLOCKS, blk, 0, stream>>>(deg);
  prep_csr_kernel<<<CSRB + CONV_BLOCKS + W_BLOCKS + 1, blk, 0, stream>>>(
      x, W1, W2, Wc, ei, xbf, WT, WcT, hb1, deg, col);
  const unsigned short* h = xbf;
  for (int l = 0; l < N_LAYERS; ++l) {
    aggregate_kernel<<<AGGR_GRID, blk, 0, stream>>>(h, deg, col, hb0);
    if (l < N_LAYERS - 1) {
      layer_pair_kernel<false><<<pair_grid, blk, 0, stream>>>(
          hb0, WT + (size_t)l * 16384, b1 + (size_t)l * 128,
          WT + (size_t)(3 + l) * 16384, b2 + (size_t)l * 128, hb1,
          nullptr, nullptr, nullptr);
      h = hb1;
    } else {
      layer_pair_kernel<true><<<pair_grid, blk, 0, stream>>>(
          hb0, WT + (size_t)l * 16384, b1 + (size_t)l * 128,
          WT + (size_t)(3 + l) * 16384, b2 + (size_t)l * 128, nullptr,
          WcT, bc, out);
    }
  }
}

// Round 10
// 238.090 us; speedup vs baseline: 2.4399x; 2.4399x over previous
//
#include <hip/hip_runtime.h>

#define N_NODES 50000
#define IN_CH 128
#define HID 128
#define OUT_CH 40
#define N_LAYERS 3
#define N_EDGES 600000
#define DSTRIDE 64    // fixed col slots/node; P(Poisson(12) > 64) ~ 1e-30
#define DEGSTRIDE 16  // 64B per counter
#define CHUNK 6250    // nodes per XCD class (N/8)

typedef __attribute__((ext_vector_type(8))) short short8;
typedef __attribute__((ext_vector_type(4))) float floatx4;

static __device__ __forceinline__ unsigned short f32_to_bf16(float f) {
  unsigned u = __float_as_uint(f);
  unsigned r = 0x7FFFu + ((u >> 16) & 1u);  // RNE
  return (unsigned short)((u + r) >> 16);
}
static __device__ __forceinline__ float bf16_to_f32(unsigned short h) {
  return __uint_as_float(((unsigned)h) << 16);
}

// ---- tiny deg-zero kernel (must complete before prep_csr's csr blocks) ----
#define ZERO_BLOCKS 782  // ceil(50000*16/4/256)
__global__ __launch_bounds__(256) void zero_deg_kernel(int* __restrict__ deg) {
  int i = (blockIdx.x * 256 + threadIdx.x) * 4;
  if (i < N_NODES * DEGSTRIDE) *(int4*)(deg + i) = make_int4(0, 0, 0, 0);
}

#define CSRB 1024         // csr blocks, FIRST in grid; co-resident so
                          // blockIdx&7 == XCD class (round-robin placement)
#define ECHUNKS 586       // ceil(600000/1024) edge chunks of 1024 edges
#define CONV_BLOCKS 6250  // (N*128/4)/256
#define W_BLOCKS 408      // (6*16384 + 48*128)/256

// == combined prep + XCD-partitioned CSR ====================================
// Verified R7: XCD class k = blockIdx&7 keeps only edges with dst in its
// 6250-node chunk -> each deg/col line is RMW'd by ONE XCD: L2-local
// atomics, no cross-XCD ping-pong, no partial-line writeback storm.
// R9 lesson: do NOT fuse further — persistent/cooperative single-kernel
// (grid.sync) pinned occupancy at the MLP phase's 52KB-LDS envelope and
// cost 2.5x (591us); the 8-dispatch DAG is the floor structure.
__global__ __launch_bounds__(256) void prep_csr_kernel(
    const float* __restrict__ x, const float* __restrict__ W1,
    const float* __restrict__ W2, const float* __restrict__ Wc,
    const int* __restrict__ ei, unsigned short* __restrict__ xb,
    unsigned short* __restrict__ WT, unsigned short* __restrict__ WcT,
    unsigned short* __restrict__ hb1, int* __restrict__ deg,
    int* __restrict__ col) {
  const int b = blockIdx.x;
  const int t = threadIdx.x;
  if (b < CSRB) {
    const int lo = (b & 7) * CHUNK;
    const int hi = lo + CHUNK;
    for (int c = (b >> 3); c < ECHUNKS; c += (CSRB >> 3)) {
      int base = (c * 256 + t) * 4;
      if (base >= N_EDGES) continue;  // N_EDGES%4==0: all-or-none per int4
      int4 s4 = *(const int4*)(ei + base);
      int4 d4 = *(const int4*)(ei + N_EDGES + base);
      if (d4.x >= lo && d4.x < hi) {
        int p = atomicAdd(&deg[(size_t)d4.x * DEGSTRIDE], 1);
        col[(size_t)d4.x * DSTRIDE + p] = s4.x;
      }
      if (d4.y >= lo && d4.y < hi) {
        int p = atomicAdd(&deg[(size_t)d4.y * DEGSTRIDE], 1);
        col[(size_t)d4.y * DSTRIDE + p] = s4.y;
      }
      if (d4.z >= lo && d4.z < hi) {
        int p = atomicAdd(&deg[(size_t)d4.z * DEGSTRIDE], 1);
        col[(size_t)d4.z * DSTRIDE + p] = s4.z;
      }
      if (d4.w >= lo && d4.w < hi) {
        int p = atomicAdd(&deg[(size_t)d4.w * DEGSTRIDE], 1);
        col[(size_t)d4.w * DSTRIDE + p] = s4.w;
      }
    }
  } else if (b < CSRB + CONV_BLOCKS) {
    int i = ((b - CSRB) * 256 + t) * 4;
    if (i < N_NODES * 128) {
      float4 v = *(const float4*)(x + i);
      ushort4 o;
      o.x = f32_to_bf16(v.x); o.y = f32_to_bf16(v.y);
      o.z = f32_to_bf16(v.z); o.w = f32_to_bf16(v.w);
      *(ushort4*)(xb + i) = o;
    }
  } else if (b < CSRB + CONV_BLOCKS + W_BLOCKS) {
    int o = (b - CSRB - CONV_BLOCKS) * 256 + t;
    if (o < 6 * 16384) {
      int mat = o >> 14;
      int r = o & 16383;
      int n = r >> 7;
      int k = r & 127;
      const float* W = (mat < 3) ? (W1 + (size_t)mat * 16384)
                                 : (W2 + (size_t)(mat - 3) * 16384);
      WT[(size_t)mat * 16384 + (size_t)n * 128 + k] =
          f32_to_bf16(W[(size_t)k * 128 + n]);
    } else if (o < 6 * 16384 + 48 * 128) {
      int r = o - 6 * 16384;
      int n = r >> 7;
      int k = r & 127;
      float v = (n < OUT_CH) ? Wc[(size_t)k * OUT_CH + n] : 0.0f;
      WcT[(size_t)n * 128 + k] = f32_to_bf16(v);
    }
  } else {
    // zero phantom rows (index N_NODES) of the two gather sources
    if (t < 128) xb[(size_t)N_NODES * 128 + t] = 0;
    else hb1[(size_t)N_NODES * 128 + (t - 128)] = 0;
  }
}

// ================= Aggregation (bf16): z = h[n] + sum_nbrs ==================
// R8 form: TWO NODES PER WAVE, R1-exact per-node lane geometry (lane owns 2
// channels; one 256B row per gather; NO cross-lane ops). 32 independent
// gathers in flight per wave. deg/col wave-uniform via readfirstlane; tail
// clamps to phantom zero row. Node->block mapping keeps the csr XCD chunking
// so deg/col reads hit their home-XCD L2. Probed variants (all neutral or
// worse): 1-node/wave, 4-row-gather, 2-row+shfl, linked-list, MLP-fused,
// coop-persistent — this is the gather path's latency equilibrium.
#define AGGR_GRID 6256  // 8 * 782 (782 blocks of 8 nodes per chunk)
__global__ __launch_bounds__(256) void aggregate_kernel(
    const unsigned short* __restrict__ h, const int* __restrict__ deg,
    const int* __restrict__ col, unsigned short* __restrict__ z) {
  const int xcd = blockIdx.x & 7;
  const int idx = blockIdx.x >> 3;
  int local = idx * 8 + (threadIdx.x >> 6) * 2;  // 2 consecutive nodes/wave
  if (local >= CHUNK) return;  // CHUNK even -> n0,n1 both valid when taken
  int n0 = __builtin_amdgcn_readfirstlane(xcd * CHUNK + local);
  int n1 = n0 + 1;
  int q = threadIdx.x & 63;
  const size_t co = (size_t)q * 2;
  ushort2 sv0 = *(const ushort2*)(h + (size_t)n0 * 128 + co);
  ushort2 sv1 = *(const ushort2*)(h + (size_t)n1 * 128 + co);
  float ax0[4], ay0[4], ax1[4], ay1[4];
#pragma unroll
  for (int k = 0; k < 4; ++k) { ax0[k] = 0.f; ay0[k] = 0.f; ax1[k] = 0.f; ay1[k] = 0.f; }
  ax0[0] = bf16_to_f32(sv0.x);
  ay0[0] = bf16_to_f32(sv0.y);
  ax1[0] = bf16_to_f32(sv1.x);
  ay1[0] = bf16_to_f32(sv1.y);
  int dg0 = __builtin_amdgcn_readfirstlane(deg[(size_t)n0 * DEGSTRIDE]);
  int dg1 = __builtin_amdgcn_readfirstlane(deg[(size_t)n1 * DEGSTRIDE]);
  int cnt = ((dg0 > dg1 ? dg0 : dg1) + 15) & ~15;
  const int* cp0 = col + (size_t)n0 * DSTRIDE;
  const int* cp1 = col + (size_t)n1 * DSTRIDE;
  for (int i = 0; i < cnt; i += 16) {
    int ss0[16], ss1[16];
#pragma unroll
    for (int k = 0; k < 16; ++k) {
      int sl0 = cp0[i + k];  // in-bounds; garbage beyond dg clamped below
      int sl1 = cp1[i + k];
      ss0[k] = __builtin_amdgcn_readfirstlane((i + k < dg0) ? sl0 : N_NODES);
      ss1[k] = __builtin_amdgcn_readfirstlane((i + k < dg1) ? sl1 : N_NODES);
    }
    ushort2 v0[16], v1[16];
#pragma unroll
    for (int k = 0; k < 16; ++k) {
      v0[k] = *(const ushort2*)(h + (size_t)ss0[k] * 128 + co);
      v1[k] = *(const ushort2*)(h + (size_t)ss1[k] * 128 + co);
    }
#pragma unroll
    for (int k = 0; k < 16; ++k) {
      ax0[k & 3] += bf16_to_f32(v0[k].x);
      ay0[k & 3] += bf16_to_f32(v0[k].y);
      ax1[k & 3] += bf16_to_f32(v1[k].x);
      ay1[k & 3] += bf16_to_f32(v1[k].y);
    }
  }
  float s0x = (ax0[0] + ax0[1]) + (ax0[2] + ax0[3]);
  float s0y = (ay0[0] + ay0[1]) + (ay0[2] + ay0[3]);
  float s1x = (ax1[0] + ax1[1]) + (ax1[2] + ax1[3]);
  float s1y = (ay1[0] + ay1[1]) + (ay1[2] + ay1[3]);
  ushort2 o0, o1;
  o0.x = f32_to_bf16(s0x);
  o0.y = f32_to_bf16(s0y);
  o1.x = f32_to_bf16(s1x);
  o1.y = f32_to_bf16(s1y);
  *(ushort2*)(z + (size_t)n0 * 128 + co) = o0;
  *(ushort2*)(z + (size_t)n1 * 128 + co) = o1;
}

// ============ Fused layer MLP: Z = relu(relu(A@W1+b1)@W2+b2) ===============
// LDS-staged weights + 16 rows/wave. 64 rows/block, 4 waves. W staged into
// LDS once per GEMM (32KB, L2-hot source); B-frags become ds_read_b128.
// LDS = 34.8K (Wl) + 17.4K (T) = 52.2K -> 3 blocks/CU. Intermediate T rows
// wave-private; barriers only around Wl restage. LAST=true fuses the
// classifier (WcT direct-global; out f32).
// Frag layouts (measured m89/m91): A/B [idx=lane&15][k=(lane>>4)*8+j];
// C/D row=(lane>>4)*4+reg, col=lane&15.
template <bool LAST>
__global__ __launch_bounds__(256) void layer_pair_kernel(
    const unsigned short* __restrict__ A, const unsigned short* __restrict__ WT1,
    const float* __restrict__ b1, const unsigned short* __restrict__ WT2,
    const float* __restrict__ b2, unsigned short* __restrict__ Z,
    const unsigned short* __restrict__ WcT, const float* __restrict__ bc,
    float* __restrict__ out, int M) {
  __shared__ __align__(16) unsigned short Wl[128][136];  // staged weight
  __shared__ __align__(16) unsigned short T[64][136];    // activations
  const int tid = threadIdx.x;
  const int w = tid >> 6;
  const int lane = tid & 63;
  const int qg = lane >> 4;
  const int ln = lane & 15;
  const int row0 = blockIdx.x * 64;
  const int rbase = w * 16;
  const int r0 = row0 + rbase + ln;
  const short8 zero8 = {0, 0, 0, 0, 0, 0, 0, 0};

  // ---- stage WT1 -> Wl (2048 chunks of 8 bf16 over 256 threads) ----
#pragma unroll
  for (int j = 0; j < 8; ++j) {
    int slot = tid + j * 256;
    int row = slot >> 4;
    int kb = slot & 15;
    *(short8*)&Wl[row][kb * 8] = *(const short8*)(WT1 + (size_t)row * 128 + kb * 8);
  }
  __syncthreads();

  // ---- GEMM1: A direct-global, B from LDS ----
  floatx4 acc[8];
#pragma unroll
  for (int ct = 0; ct < 8; ++ct) acc[ct] = (floatx4){0.f, 0.f, 0.f, 0.f};
#pragma unroll
  for (int ks = 0; ks < 4; ++ks) {
    const int koff = ks * 32 + qg * 8;
    short8 a = (r0 < M) ? *(const short8*)(A + (size_t)r0 * 128 + koff) : zero8;
#pragma unroll
    for (int ct = 0; ct < 8; ++ct) {
      short8 b = *(const short8*)&Wl[ct * 16 + ln][koff];
      acc[ct] = __builtin_amdgcn_mfma_f32_16x16x32_bf16(a, b, acc[ct], 0, 0, 0);
    }
  }
  // ---- epilogue1 -> wave-private T rows (bias+relu+bf16) ----
#pragma unroll
  for (int ct = 0; ct < 8; ++ct) {
    float bv = b1[ct * 16 + ln];
#pragma unroll
    for (int r = 0; r < 4; ++r) {
      float v = fmaxf(acc[ct][r] + bv, 0.0f);
      T[rbase + qg * 4 + r][ct * 16 + ln] = f32_to_bf16(v);
    }
  }

  // ---- restage Wl with WT2 (all waves must be done with WT1) ----
  __syncthreads();
#pragma unroll
  for (int j = 0; j < 8; ++j) {
    int slot = tid + j * 256;
    int row = slot >> 4;
    int kb = slot & 15;
    *(short8*)&Wl[row][kb * 8] = *(const short8*)(WT2 + (size_t)row * 128 + kb * 8);
  }
  __syncthreads();

  // ---- GEMM2: A from own T rows, B from LDS ----
  floatx4 acc2[8];
#pragma unroll
  for (int ct = 0; ct < 8; ++ct) acc2[ct] = (floatx4){0.f, 0.f, 0.f, 0.f};
#pragma unroll
  for (int ks = 0; ks < 4; ++ks) {
    const int koff = ks * 32 + qg * 8;
    short8 a = *(const short8*)&T[rbase + ln][koff];
#pragma unroll
    for (int ct = 0; ct < 8; ++ct) {
      short8 b = *(const short8*)&Wl[ct * 16 + ln][koff];
      acc2[ct] = __builtin_amdgcn_mfma_f32_16x16x32_bf16(a, b, acc2[ct], 0, 0, 0);
    }
  }
  // ---- epilogue2 -> own T rows ----
#pragma unroll
  for (int ct = 0; ct < 8; ++ct) {
    float bv = b2[ct * 16 + ln];
#pragma unroll
    for (int r = 0; r < 4; ++r) {
      float v = fmaxf(acc2[ct][r] + bv, 0.0f);
      T[rbase + qg * 4 + r][ct * 16 + ln] = f32_to_bf16(v);
    }
  }

  if (LAST) {
    // ---- GEMM3 (classifier): A from own T rows, B = WcT direct-global ----
    floatx4 acc3[3];
#pragma unroll
    for (int ct = 0; ct < 3; ++ct) acc3[ct] = (floatx4){0.f, 0.f, 0.f, 0.f};
#pragma unroll
    for (int ks = 0; ks < 4; ++ks) {
      const int koff = ks * 32 + qg * 8;
      short8 a = *(const short8*)&T[rbase + ln][koff];
#pragma unroll
      for (int ct = 0; ct < 3; ++ct) {
        short8 b = *(const short8*)(WcT + (size_t)(ct * 16 + ln) * 128 + koff);
        acc3[ct] = __builtin_amdgcn_mfma_f32_16x16x32_bf16(a, b, acc3[ct], 0, 0, 0);
      }
    }
#pragma unroll
    for (int ct = 0; ct < 3; ++ct) {
      int colg = ct * 16 + ln;
      if (colg < OUT_CH) {
        float bv = bc[colg];
#pragma unroll
        for (int r = 0; r < 4; ++r) {
          int row = row0 + rbase + qg * 4 + r;
          if (row < M) out[(size_t)row * OUT_CH + colg] = acc3[ct][r] + bv;
        }
      }
    }
  } else {
    __syncthreads();
    // ---- cooperative coalesced store: 64 rows x 256B ----
#pragma unroll
    for (int j = 0; j < 4; ++j) {
      int slot = tid + j * 256;  // 0..1023 chunks of 8 bf16
      int row = slot >> 4;
      int kb = slot & 15;
      if (row0 + row < M) {
        short8 v = *(const short8*)&T[row][kb * 8];
        *(short8*)(Z + (size_t)(row0 + row) * 128 + kb * 8) = v;
      }
    }
  }
}

// ---------------------------------------------------------------------------
extern "C" void kernel_launch(void* const* d_in, const int* in_sizes, int n_in,
                              void* d_out, int out_size, void* d_ws,
                              size_t ws_size, hipStream_t stream) {
  const float* x = (const float*)d_in[0];
  const int* ei = (const int*)d_in[2];  // int32 [2, E]
  const float* W1 = (const float*)d_in[3];
  const float* b1 = (const float*)d_in[4];
  const float* W2 = (const float*)d_in[5];
  const float* b2 = (const float*)d_in[6];
  const float* Wc = (const float*)d_in[7];
  const float* bc = (const float*)d_in[8];
  float* out = (float*)d_out;

  // Node buffers have N+1 rows: row N_NODES is the phantom zero row.
  const size_t NF = (size_t)(N_NODES + 1) * 128;
  unsigned short* hb0 = (unsigned short*)d_ws;
  unsigned short* hb1 = hb0 + NF;
  unsigned short* xbf = hb1 + NF;
  unsigned short* WT = xbf + NF;         // 6*16384 bf16
  unsigned short* WcT = WT + 6 * 16384;  // 48*128 bf16
  int* deg = (int*)(WcT + 48 * 128);     // [N * DEGSTRIDE] (64B-padded ctrs)
  int* col = deg + (size_t)N_NODES * DEGSTRIDE;  // [N * DSTRIDE]

  const dim3 blk(256);
  const int pair_grid = (N_NODES + 63) / 64;  // 782

  // ---- deg = 0 (tiny; must complete before prep_csr's csr blocks) ----
  zero_deg_kernel<<<ZERO_BLOCKS, blk, 0, stream>>>(deg);

  // ---- combined prep + XCD-partitioned CSR ----
  prep_csr_kernel<<<CSRB + CONV_BLOCKS + W_BLOCKS + 1, blk, 0, stream>>>(
      x, W1, W2, Wc, ei, xbf, WT, WcT, hb1, deg, col);

  // ---- 3 GIN layers; classifier fused into the last pair ----
  // Fixed buffers: agg h->hb0; pair hb0->hb1; next h = hb1 (old h dead).
  const unsigned short* h = xbf;
  for (int l = 0; l < N_LAYERS; ++l) {
    aggregate_kernel<<<AGGR_GRID, blk, 0, stream>>>(h, deg, col, hb0);
    if (l < N_LAYERS - 1) {
      layer_pair_kernel<false><<<pair_grid, blk, 0, stream>>>(
          hb0, WT + (size_t)l * 16384, b1 + (size_t)l * 128,
          WT + (size_t)(3 + l) * 16384, b2 + (size_t)l * 128, hb1,
          nullptr, nullptr, nullptr, N_NODES);
      h = hb1;
    } else {
      layer_pair_kernel<true><<<pair_grid, blk, 0, stream>>>(
          hb0, WT + (size_t)l * 16384, b1 + (size_t)l * 128,
          WT + (size_t)(3 + l) * 16384, b2 + (size_t)l * 128, nullptr,
          WcT, bc, out, N_NODES);
    }
  }
}